// Round 8
// baseline (87.759 us; speedup 1.0000x reference)
//
#include <hip/hip_runtime.h>

// YOLOv1 loss, forward only. preds/targets: (16384,7,7,30) f32 -> scalar f32.
//   coo=(T4>0), noo=(T4==0)
//   noobj   = noo * ((P4-T4)^2 + (P9-T9)^2)
//   iou_b   = IoU(pred box b, pred box 0)   (reference quirk: tbox = pred box 0)
//   idx     = argmax(iou)  [np: first max; NaN acts as max]
//   loss += coo*((P[5i+4]-max_iou)^2 + 0.5*P[5(1-i)+4]^2) + 0.5*noobj
// total = sum / 16384.  (loc_loss and class_loss are exactly 0.)
//
// R7: fuse the final reduction (last-block-done) to remove the 2nd kernel
// launch (~3-4us serialized in the graph). Evidence so far: memory phase
// invariant at ~36-37us across occupancy 28-60%, 5-10 loads in flight,
// scattered/coalesced/DMA staging -> bound by irreducible 192MB line
// traffic at ~5.7-5.9 TB/s (~92% of 6.29 TB/s D2D ceiling).
// Loss kernel structure = R5 (fastest, zero bank conflicts).

#define TILE 256   // cells per tile; 128 pairs
#define NT   2     // tiles per block -> grid 1568

__device__ __forceinline__ float cell_loss(const float p[10], float t4, float t9) {
    float coo = (t4 > 0.0f) ? 1.0f : 0.0f;
    float noo = (t4 == 0.0f) ? 1.0f : 0.0f;

    float d4 = p[4] - t4;
    float d9 = p[9] - t9;
    float noo_term = noo * (d4 * d4 + d9 * d9);

    // "target" box for IoU = pred box 0 (reference quirk)
    float lt2x = p[0] / 14.0f - 0.5f * p[2];
    float lt2y = p[1] / 14.0f - 0.5f * p[3];
    float rb2x = p[0] / 14.0f + 0.5f * p[2];
    float rb2y = p[1] / 14.0f + 0.5f * p[3];
    float area2 = (rb2x - lt2x) * (rb2y - lt2y);

    float iou[2];
    #pragma unroll
    for (int b = 0; b < 2; ++b) {
        float x = p[5 * b] / 14.0f;
        float y = p[5 * b + 1] / 14.0f;
        float w = p[5 * b + 2];
        float h = p[5 * b + 3];
        float lt1x = x - 0.5f * w, lt1y = y - 0.5f * h;
        float rb1x = x + 0.5f * w, rb1y = y + 0.5f * h;
        float iltx = fmaxf(lt1x, lt2x), ilty = fmaxf(lt1y, lt2y);
        float irbx = fminf(rb1x, rb2x), irby = fminf(rb1y, rb2y);
        float iwx = fmaxf(irbx - iltx, 0.0f);
        float iwy = fmaxf(irby - ilty, 0.0f);
        float inter = iwx * iwy;
        float area1 = (rb1x - lt1x) * (rb1y - lt1y);
        iou[b] = inter / (area1 + area2 - inter);
    }

    // np.argmax: first occurrence of max; NaN compares as maximum.
    int idx;
    float max_iou;
    if (isnan(iou[0]))      { idx = 0; max_iou = iou[0]; }
    else if (isnan(iou[1])) { idx = 1; max_iou = iou[1]; }
    else                    { idx = (iou[1] > iou[0]) ? 1 : 0;
                              max_iou = fmaxf(iou[0], iou[1]); }

    float resp4  = p[5 * idx + 4];
    float nresp4 = p[5 * (1 - idx) + 4];
    float cdiff  = resp4 - max_iou;
    return coo * (cdiff * cdiff + 0.5f * nresp4 * nresp4) + 0.5f * noo_term;
}

struct TileRegs { float4 pv[3]; float4 tv[2]; };

__device__ __forceinline__ void issue_tile(const float* __restrict__ preds,
                                           const float* __restrict__ targets,
                                           long tile0, int tid, TileRegs& R) {
    const float4* gp = reinterpret_cast<const float4*>(preds + tile0 * 30);
    const float4* gt = reinterpret_cast<const float4*>(targets + tile0 * 30);
    #pragma unroll
    for (int k = 0; k < 3; ++k) {           // 768 = 128 pairs * 6 pred cols
        int L = tid + 256 * k;
        int pair = L / 6, rr = L - pair * 6;
        int r = (rr < 3) ? rr : rr + 4;     // {0,1,2,7,8,9}
        R.pv[k] = gp[pair * 15 + r];
    }
    #pragma unroll
    for (int k = 0; k < 2; ++k) {           // 512 = 128 pairs * 4 target cols
        int L = tid + 256 * k;
        int pair = L / 4, rr = L & 3;
        int r = (rr < 2) ? rr + 1 : rr + 6; // {1,2,8,9}
        R.tv[k] = gt[pair * 15 + r];
    }
}

__device__ __forceinline__ void write_tile(float4* smem4, float2* S2, float* Tc,
                                           int tid, const TileRegs& R) {
    #pragma unroll
    for (int k = 0; k < 3; ++k) {
        int L = tid + 256 * k;
        int pair = L / 6, rr = L - pair * 6;
        if (rr == 2)      S2[(pair * 5 + 2) * 2]     = make_float2(R.pv[k].x, R.pv[k].y);
        else if (rr == 3) S2[(pair * 5 + 2) * 2 + 1] = make_float2(R.pv[k].z, R.pv[k].w);
        else { int slot = (rr < 2) ? rr : rr - 1; smem4[pair * 5 + slot] = R.pv[k]; }
    }
    #pragma unroll
    for (int k = 0; k < 2; ++k) {
        int L = tid + 256 * k;
        int pair = L / 4, rr = L & 3;
        float v = (rr == 0) ? R.tv[k].x : (rr == 1) ? R.tv[k].y
                : (rr == 2) ? R.tv[k].z : R.tv[k].w;
        Tc[pair * 4 + rr] = v;
    }
}

__device__ __forceinline__ float compute_tile(const float2* S2, const float* Tc, int tid) {
    float p[10];
    #pragma unroll
    for (int k = 0; k < 5; ++k) {
        float2 q = S2[5 * tid + k];
        p[2 * k]     = q.x;
        p[2 * k + 1] = q.y;
    }
    return cell_loss(p, Tc[2 * tid], Tc[2 * tid + 1]);
}

__global__ __launch_bounds__(256) void yolo_loss_kernel(
    const float* __restrict__ preds,
    const float* __restrict__ targets,
    float* __restrict__ partials,
    unsigned* __restrict__ counter,
    float* __restrict__ out,
    int ncells, int nblocks)
{
    __shared__ float4 smem4[768];  // [0,640) preds compact, [640,768) targets compact
    __shared__ float  warp_sums[4];
    __shared__ int    is_last;
    float2* S2 = reinterpret_cast<float2*>(smem4);
    float*  Tc = reinterpret_cast<float*>(smem4 + 640);

    const int tid = threadIdx.x;
    const long tA = (long)blockIdx.x * (NT * TILE);
    const long tB = tA + TILE;
    float contrib = 0.0f;

    if (tB + TILE <= ncells) {
        TileRegs A, B;
        issue_tile(preds, targets, tA, tid, A);
        write_tile(smem4, S2, Tc, tid, A);
        __syncthreads();
        issue_tile(preds, targets, tB, tid, B);
        contrib = compute_tile(S2, Tc, tid);
        __syncthreads();
        write_tile(smem4, S2, Tc, tid, B);
        __syncthreads();
        contrib += compute_tile(S2, Tc, tid);
    } else {
        // generic tail fallback (unused: 802816 = 1568 * 512)
        #pragma unroll
        for (int t = 0; t < NT; ++t) {
            long cell = tA + (long)t * TILE + tid;
            if (cell < ncells) {
                long base = cell * 30;
                float p[10];
                #pragma unroll
                for (int k = 0; k < 5; ++k) {
                    float2 v = *reinterpret_cast<const float2*>(preds + base + 2 * k);
                    p[2 * k] = v.x;
                    p[2 * k + 1] = v.y;
                }
                contrib += cell_loss(p, targets[base + 4], targets[base + 9]);
            }
        }
    }

    // wave (64-lane) shuffle reduce -> per-block sum
    #pragma unroll
    for (int off = 32; off > 0; off >>= 1)
        contrib += __shfl_down(contrib, off, 64);

    int lane = tid & 63;
    int wid  = tid >> 6;
    if (lane == 0) warp_sums[wid] = contrib;
    __syncthreads();

    // publish partial; last block to arrive reduces all partials
    if (tid == 0) {
        float bsum = warp_sums[0] + warp_sums[1] + warp_sums[2] + warp_sums[3];
        partials[blockIdx.x] = bsum;
        __threadfence();   // device-scope: partial visible before counter bump
        unsigned done = atomicAdd(counter, 1u);
        is_last = (done == (unsigned)(nblocks - 1)) ? 1 : 0;
    }
    __syncthreads();

    if (is_last) {
        float s = 0.0f;
        for (int i = tid; i < nblocks; i += 256) {
            // device-scope atomic load: bypass potentially-stale L1/L2
            s += __hip_atomic_load(&partials[i], __ATOMIC_RELAXED,
                                   __HIP_MEMORY_SCOPE_AGENT);
        }
        #pragma unroll
        for (int off = 32; off > 0; off >>= 1)
            s += __shfl_down(s, off, 64);
        if (lane == 0) warp_sums[wid] = s;
        __syncthreads();
        if (tid == 0) {
            out[0] = (warp_sums[0] + warp_sums[1] + warp_sums[2] + warp_sums[3])
                     * (1.0f / 16384.0f);
        }
    }
}

extern "C" void kernel_launch(void* const* d_in, const int* in_sizes, int n_in,
                              void* d_out, int out_size, void* d_ws, size_t ws_size,
                              hipStream_t stream) {
    const float* preds   = (const float*)d_in[0];
    const float* targets = (const float*)d_in[1];
    float* out = (float*)d_out;

    float*    partials = (float*)d_ws;                       // [0, 1568) floats
    unsigned* counter  = (unsigned*)((char*)d_ws + 8192);    // own cache line region

    int ncells = in_sizes[0] / 30;                       // 802816
    int grid = (ncells + NT * TILE - 1) / (NT * TILE);   // 1568

    hipMemsetAsync(counter, 0, sizeof(unsigned), stream);

    yolo_loss_kernel<<<grid, 256, 0, stream>>>(preds, targets, partials,
                                               counter, out, ncells, grid);
}

// Round 9
// 36.642 us; speedup vs baseline: 2.3950x; 2.3950x over previous
//
#include <hip/hip_runtime.h>

// YOLOv1 loss, forward only. preds/targets: (16384,7,7,30) f32 -> scalar f32.
//   coo=(T4>0), noo=(T4==0)
//   noobj   = noo * ((P4-T4)^2 + (P9-T9)^2)
//   iou_b   = IoU(pred box b, pred box 0)   (reference quirk: tbox = pred box 0)
//   idx     = argmax(iou)  [np: first max; NaN acts as max]
//   loss += coo*((P[5i+4]-max_iou)^2 + 0.5*P[5(1-i)+4]^2) + 0.5*noobj
// total = sum / 16384.  (loc_loss and class_loss are exactly 0.)
//
// R8: REVERT to R5 (best: 36.5us). R7's fused last-block reduction
// (__threadfence + device-scope atomics) slowed the whole stream 2x --
// cross-XCD sync inside a hot kernel serializes against streaming on the
// fabric. Two-kernel structure is structurally optimal here.
// Ledger: streaming phase invariant ~33-34us across occupancy 28-60%,
// requested-bytes 64-192MB, scattered/coalesced/DMA staging. 192MB of
// 128B-line traffic is irreducible (needed-byte gaps < 128B) ->
// 192MB/33.5us = 5.7-5.9 TB/s ~= 91% of 6.29 TB/s measured D2D ceiling.
// FETCH_SIZE ~96MB == 32B-sector-granular fetch of exactly the needed
// ranges (72 B/cell preds + 48 B/cell targets). Fabric-BW roofline.

#define TILE 256   // cells per tile; 128 pairs
#define NT   2     // tiles per block -> grid 1568

__device__ __forceinline__ float cell_loss(const float p[10], float t4, float t9) {
    float coo = (t4 > 0.0f) ? 1.0f : 0.0f;
    float noo = (t4 == 0.0f) ? 1.0f : 0.0f;

    float d4 = p[4] - t4;
    float d9 = p[9] - t9;
    float noo_term = noo * (d4 * d4 + d9 * d9);

    // "target" box for IoU = pred box 0 (reference quirk)
    float lt2x = p[0] / 14.0f - 0.5f * p[2];
    float lt2y = p[1] / 14.0f - 0.5f * p[3];
    float rb2x = p[0] / 14.0f + 0.5f * p[2];
    float rb2y = p[1] / 14.0f + 0.5f * p[3];
    float area2 = (rb2x - lt2x) * (rb2y - lt2y);

    float iou[2];
    #pragma unroll
    for (int b = 0; b < 2; ++b) {
        float x = p[5 * b] / 14.0f;
        float y = p[5 * b + 1] / 14.0f;
        float w = p[5 * b + 2];
        float h = p[5 * b + 3];
        float lt1x = x - 0.5f * w, lt1y = y - 0.5f * h;
        float rb1x = x + 0.5f * w, rb1y = y + 0.5f * h;
        float iltx = fmaxf(lt1x, lt2x), ilty = fmaxf(lt1y, lt2y);
        float irbx = fminf(rb1x, rb2x), irby = fminf(rb1y, rb2y);
        float iwx = fmaxf(irbx - iltx, 0.0f);
        float iwy = fmaxf(irby - ilty, 0.0f);
        float inter = iwx * iwy;
        float area1 = (rb1x - lt1x) * (rb1y - lt1y);
        iou[b] = inter / (area1 + area2 - inter);
    }

    // np.argmax: first occurrence of max; NaN compares as maximum.
    int idx;
    float max_iou;
    if (isnan(iou[0]))      { idx = 0; max_iou = iou[0]; }
    else if (isnan(iou[1])) { idx = 1; max_iou = iou[1]; }
    else                    { idx = (iou[1] > iou[0]) ? 1 : 0;
                              max_iou = fmaxf(iou[0], iou[1]); }

    float resp4  = p[5 * idx + 4];
    float nresp4 = p[5 * (1 - idx) + 4];
    float cdiff  = resp4 - max_iou;
    return coo * (cdiff * cdiff + 0.5f * nresp4 * nresp4) + 0.5f * noo_term;
}

struct TileRegs { float4 pv[3]; float4 tv[2]; };

// issue global loads for one 256-cell tile into registers
__device__ __forceinline__ void issue_tile(const float* __restrict__ preds,
                                           const float* __restrict__ targets,
                                           long tile0, int tid, TileRegs& R) {
    const float4* gp = reinterpret_cast<const float4*>(preds + tile0 * 30);
    const float4* gt = reinterpret_cast<const float4*>(targets + tile0 * 30);
    #pragma unroll
    for (int k = 0; k < 3; ++k) {           // 768 = 128 pairs * 6 pred cols
        int L = tid + 256 * k;
        int pair = L / 6, rr = L - pair * 6;
        int r = (rr < 3) ? rr : rr + 4;     // {0,1,2,7,8,9}
        R.pv[k] = gp[pair * 15 + r];
    }
    #pragma unroll
    for (int k = 0; k < 2; ++k) {           // 512 = 128 pairs * 4 target cols
        int L = tid + 256 * k;
        int pair = L / 4, rr = L & 3;
        int r = (rr < 2) ? rr + 1 : rr + 6; // {1,2,8,9}
        R.tv[k] = gt[pair * 15 + r];
    }
}

// compact registers into LDS:
//   preds: cell c's 10 floats contiguous at float offset 10c
//   targets: Tc[2c]=t4, Tc[2c+1]=t9
__device__ __forceinline__ void write_tile(float4* smem4, float2* S2, float* Tc,
                                           int tid, const TileRegs& R) {
    #pragma unroll
    for (int k = 0; k < 3; ++k) {
        int L = tid + 256 * k;
        int pair = L / 6, rr = L - pair * 6;
        if (rr == 2)      S2[(pair * 5 + 2) * 2]     = make_float2(R.pv[k].x, R.pv[k].y);
        else if (rr == 3) S2[(pair * 5 + 2) * 2 + 1] = make_float2(R.pv[k].z, R.pv[k].w);
        else { int slot = (rr < 2) ? rr : rr - 1; smem4[pair * 5 + slot] = R.pv[k]; }
    }
    #pragma unroll
    for (int k = 0; k < 2; ++k) {
        int L = tid + 256 * k;
        int pair = L / 4, rr = L & 3;
        float v = (rr == 0) ? R.tv[k].x : (rr == 1) ? R.tv[k].y
                : (rr == 2) ? R.tv[k].z : R.tv[k].w;
        Tc[pair * 4 + rr] = v;
    }
}

__device__ __forceinline__ float compute_tile(const float2* S2, const float* Tc, int tid) {
    float p[10];
    #pragma unroll
    for (int k = 0; k < 5; ++k) {
        float2 q = S2[5 * tid + k];
        p[2 * k]     = q.x;
        p[2 * k + 1] = q.y;
    }
    return cell_loss(p, Tc[2 * tid], Tc[2 * tid + 1]);
}

__global__ __launch_bounds__(256) void yolo_loss_kernel(
    const float* __restrict__ preds,
    const float* __restrict__ targets,
    float* __restrict__ partials,
    int ncells)
{
    __shared__ float4 smem4[768];  // [0,640) preds compact, [640,768) targets compact
    __shared__ float  warp_sums[4];
    float2* S2 = reinterpret_cast<float2*>(smem4);
    float*  Tc = reinterpret_cast<float*>(smem4 + 640);

    const int tid = threadIdx.x;
    const long tA = (long)blockIdx.x * (NT * TILE);
    const long tB = tA + TILE;
    float contrib = 0.0f;

    if (tB + TILE <= ncells) {
        TileRegs A, B;
        issue_tile(preds, targets, tA, tid, A);
        write_tile(smem4, S2, Tc, tid, A);
        __syncthreads();
        issue_tile(preds, targets, tB, tid, B);   // prefetch: overlaps compute of A
        contrib = compute_tile(S2, Tc, tid);
        __syncthreads();                          // LDS of A fully consumed
        write_tile(smem4, S2, Tc, tid, B);
        __syncthreads();
        contrib += compute_tile(S2, Tc, tid);
    } else {
        // generic tail fallback (unused: 802816 = 1568 * 512): direct loads
        #pragma unroll
        for (int t = 0; t < NT; ++t) {
            long cell = tA + (long)t * TILE + tid;
            if (cell < ncells) {
                long base = cell * 30;
                float p[10];
                #pragma unroll
                for (int k = 0; k < 5; ++k) {
                    float2 v = *reinterpret_cast<const float2*>(preds + base + 2 * k);
                    p[2 * k] = v.x;
                    p[2 * k + 1] = v.y;
                }
                contrib += cell_loss(p, targets[base + 4], targets[base + 9]);
            }
        }
    }

    // wave (64-lane) shuffle reduce
    #pragma unroll
    for (int off = 32; off > 0; off >>= 1)
        contrib += __shfl_down(contrib, off, 64);

    int lane = tid & 63;
    int wid  = tid >> 6;
    if (lane == 0) warp_sums[wid] = contrib;
    __syncthreads();

    if (tid == 0) {
        partials[blockIdx.x] = warp_sums[0] + warp_sums[1] + warp_sums[2] + warp_sums[3];
    }
}

__global__ __launch_bounds__(256) void yolo_reduce_kernel(
    const float* __restrict__ partials,
    float* __restrict__ out,
    int nparts)
{
    __shared__ float warp_sums[4];
    const int tid = threadIdx.x;

    float s = 0.0f;
    for (int i = tid; i < nparts; i += 256)
        s += partials[i];

    #pragma unroll
    for (int off = 32; off > 0; off >>= 1)
        s += __shfl_down(s, off, 64);

    int lane = tid & 63;
    int wid  = tid >> 6;
    if (lane == 0) warp_sums[wid] = s;
    __syncthreads();

    if (tid == 0) {
        out[0] = (warp_sums[0] + warp_sums[1] + warp_sums[2] + warp_sums[3])
                 * (1.0f / 16384.0f);
    }
}

extern "C" void kernel_launch(void* const* d_in, const int* in_sizes, int n_in,
                              void* d_out, int out_size, void* d_ws, size_t ws_size,
                              hipStream_t stream) {
    const float* preds   = (const float*)d_in[0];
    const float* targets = (const float*)d_in[1];
    float* out = (float*)d_out;
    float* partials = (float*)d_ws;

    int ncells = in_sizes[0] / 30;                       // 802816
    int grid = (ncells + NT * TILE - 1) / (NT * TILE);   // 1568

    yolo_loss_kernel<<<grid, 256, 0, stream>>>(preds, targets, partials, ncells);
    yolo_reduce_kernel<<<1, 256, 0, stream>>>(partials, out, grid);
}

// Round 10
// 36.469 us; speedup vs baseline: 2.4064x; 1.0047x over previous
//
#include <hip/hip_runtime.h>

// YOLOv1 loss, forward only. preds/targets: (16384,7,7,30) f32 -> scalar f32.
//   coo=(T4>0), noo=(T4==0)
//   noobj   = noo * ((P4-T4)^2 + (P9-T9)^2)
//   iou_b   = IoU(pred box b, pred box 0)   (reference quirk: tbox = pred box 0)
//   idx     = argmax(iou)  [np: first max; NaN acts as max]
//   loss += coo*((P[5i+4]-max_iou)^2 + 0.5*P[5(1-i)+4]^2) + 0.5*noobj
// total = sum / 16384.  (loc_loss and class_loss are exactly 0.)
//
// R9: GRANULARITY PROBE. R5/R8 best = 36.5us. Before calling it a line-BW
// roofline, test whether L3/L2 transfers are line- or sector-granular:
// stage with FULLY DENSE float4 reads (every byte of both arrays requested
// once; wave-load = 1024B contiguous) instead of R5's holey gather (same
// touched lines, 128 vs 192 MB requested). Unused values kept live via
// asm volatile (DCE guard). Pre-committed reads:
//   unchanged -> line-granular, 5.7 TB/s fabric roofline confirmed -> ROOFLINE
//   ~1.4x slower + FETCH ~189MB -> sector-granular, revert to R5
//   faster -> wave-span coalescing was the binder, iterate

#define TILE 256   // cells per tile; 128 pairs; 1920 float4 per array per tile
#define NT   2     // tiles per block -> grid 1568

__device__ __forceinline__ float cell_loss(const float p[10], float t4, float t9) {
    float coo = (t4 > 0.0f) ? 1.0f : 0.0f;
    float noo = (t4 == 0.0f) ? 1.0f : 0.0f;

    float d4 = p[4] - t4;
    float d9 = p[9] - t9;
    float noo_term = noo * (d4 * d4 + d9 * d9);

    // "target" box for IoU = pred box 0 (reference quirk)
    float lt2x = p[0] / 14.0f - 0.5f * p[2];
    float lt2y = p[1] / 14.0f - 0.5f * p[3];
    float rb2x = p[0] / 14.0f + 0.5f * p[2];
    float rb2y = p[1] / 14.0f + 0.5f * p[3];
    float area2 = (rb2x - lt2x) * (rb2y - lt2y);

    float iou[2];
    #pragma unroll
    for (int b = 0; b < 2; ++b) {
        float x = p[5 * b] / 14.0f;
        float y = p[5 * b + 1] / 14.0f;
        float w = p[5 * b + 2];
        float h = p[5 * b + 3];
        float lt1x = x - 0.5f * w, lt1y = y - 0.5f * h;
        float rb1x = x + 0.5f * w, rb1y = y + 0.5f * h;
        float iltx = fmaxf(lt1x, lt2x), ilty = fmaxf(lt1y, lt2y);
        float irbx = fminf(rb1x, rb2x), irby = fminf(rb1y, rb2y);
        float iwx = fmaxf(irbx - iltx, 0.0f);
        float iwy = fmaxf(irby - ilty, 0.0f);
        float inter = iwx * iwy;
        float area1 = (rb1x - lt1x) * (rb1y - lt1y);
        iou[b] = inter / (area1 + area2 - inter);
    }

    // np.argmax: first occurrence of max; NaN compares as maximum.
    int idx;
    float max_iou;
    if (isnan(iou[0]))      { idx = 0; max_iou = iou[0]; }
    else if (isnan(iou[1])) { idx = 1; max_iou = iou[1]; }
    else                    { idx = (iou[1] > iou[0]) ? 1 : 0;
                              max_iou = fmaxf(iou[0], iou[1]); }

    float resp4  = p[5 * idx + 4];
    float nresp4 = p[5 * (1 - idx) + 4];
    float cdiff  = resp4 - max_iou;
    return coo * (cdiff * cdiff + 0.5f * nresp4 * nresp4) + 0.5f * noo_term;
}

__device__ __forceinline__ void keep_alive(const float4& v) {
    asm volatile("" :: "v"(v.x), "v"(v.y), "v"(v.z), "v"(v.w));
}

// DENSE stage of one 256-cell tile: read all 1920 float4 of each array,
// filter to compact LDS layout in registers.
//   preds slot map per pair (5 float4): r=0->s0, r=1->s1, r=2->s2.xy,
//     r=7->s2.zw, r=8->s3, r=9->s4   (others loaded, kept live, discarded)
//   targets: r=1->Tc[4p]=v.x, r=2->Tc[4p+1]=v.y, r=8->Tc[4p+2]=v.z,
//     r=9->Tc[4p+3]=v.w
__device__ __forceinline__ void stage_tile_dense(const float4* __restrict__ gp,
                                                 const float4* __restrict__ gt,
                                                 float4* smem4, float2* S2, float* Tc,
                                                 int tid) {
    #pragma unroll
    for (int k = 0; k < 8; ++k) {
        int j = tid + 256 * k;
        if (j < 1920) {
            float4 v = gp[j];
            keep_alive(v);                      // DCE guard for discarded columns
            int pair = j / 15, r = j - pair * 15;
            if (r == 2)      S2[(pair * 5 + 2) * 2]     = make_float2(v.x, v.y);
            else if (r == 7) S2[(pair * 5 + 2) * 2 + 1] = make_float2(v.z, v.w);
            else if (r < 2)  smem4[pair * 5 + r] = v;
            else if (r == 8 || r == 9) smem4[pair * 5 + r - 5] = v;
        }
    }
    #pragma unroll
    for (int k = 0; k < 8; ++k) {
        int j = tid + 256 * k;
        if (j < 1920) {
            float4 v = gt[j];
            keep_alive(v);
            int pair = j / 15, r = j - pair * 15;
            if (r == 1)      Tc[pair * 4 + 0] = v.x;
            else if (r == 2) Tc[pair * 4 + 1] = v.y;
            else if (r == 8) Tc[pair * 4 + 2] = v.z;
            else if (r == 9) Tc[pair * 4 + 3] = v.w;
        }
    }
}

__device__ __forceinline__ float compute_tile(const float2* S2, const float* Tc, int tid) {
    float p[10];
    #pragma unroll
    for (int k = 0; k < 5; ++k) {
        float2 q = S2[5 * tid + k];
        p[2 * k]     = q.x;
        p[2 * k + 1] = q.y;
    }
    return cell_loss(p, Tc[2 * tid], Tc[2 * tid + 1]);
}

__global__ __launch_bounds__(256) void yolo_loss_kernel(
    const float* __restrict__ preds,
    const float* __restrict__ targets,
    float* __restrict__ partials,
    int ncells)
{
    __shared__ float4 smem4[768];  // [0,640) preds compact, [640,768) targets compact
    __shared__ float  warp_sums[4];
    float2* S2 = reinterpret_cast<float2*>(smem4);
    float*  Tc = reinterpret_cast<float*>(smem4 + 640);

    const int tid = threadIdx.x;
    const long tA = (long)blockIdx.x * (NT * TILE);
    float contrib = 0.0f;

    if (tA + NT * TILE <= ncells) {
        #pragma unroll
        for (int t = 0; t < NT; ++t) {
            long tile0 = tA + (long)t * TILE;
            if (t) __syncthreads();   // prev compute's LDS reads done before overwrite
            stage_tile_dense(reinterpret_cast<const float4*>(preds + tile0 * 30),
                             reinterpret_cast<const float4*>(targets + tile0 * 30),
                             smem4, S2, Tc, tid);
            __syncthreads();
            contrib += compute_tile(S2, Tc, tid);
        }
    } else {
        // generic tail fallback (unused: 802816 = 1568 * 512): direct loads
        #pragma unroll
        for (int t = 0; t < NT; ++t) {
            long cell = tA + (long)t * TILE + tid;
            if (cell < ncells) {
                long base = cell * 30;
                float p[10];
                #pragma unroll
                for (int k = 0; k < 5; ++k) {
                    float2 v = *reinterpret_cast<const float2*>(preds + base + 2 * k);
                    p[2 * k] = v.x;
                    p[2 * k + 1] = v.y;
                }
                contrib += cell_loss(p, targets[base + 4], targets[base + 9]);
            }
        }
    }

    // wave (64-lane) shuffle reduce
    #pragma unroll
    for (int off = 32; off > 0; off >>= 1)
        contrib += __shfl_down(contrib, off, 64);

    int lane = tid & 63;
    int wid  = tid >> 6;
    if (lane == 0) warp_sums[wid] = contrib;
    __syncthreads();

    if (tid == 0) {
        partials[blockIdx.x] = warp_sums[0] + warp_sums[1] + warp_sums[2] + warp_sums[3];
    }
}

__global__ __launch_bounds__(256) void yolo_reduce_kernel(
    const float* __restrict__ partials,
    float* __restrict__ out,
    int nparts)
{
    __shared__ float warp_sums[4];
    const int tid = threadIdx.x;

    float s = 0.0f;
    for (int i = tid; i < nparts; i += 256)
        s += partials[i];

    #pragma unroll
    for (int off = 32; off > 0; off >>= 1)
        s += __shfl_down(s, off, 64);

    int lane = tid & 63;
    int wid  = tid >> 6;
    if (lane == 0) warp_sums[wid] = s;
    __syncthreads();

    if (tid == 0) {
        out[0] = (warp_sums[0] + warp_sums[1] + warp_sums[2] + warp_sums[3])
                 * (1.0f / 16384.0f);
    }
}

extern "C" void kernel_launch(void* const* d_in, const int* in_sizes, int n_in,
                              void* d_out, int out_size, void* d_ws, size_t ws_size,
                              hipStream_t stream) {
    const float* preds   = (const float*)d_in[0];
    const float* targets = (const float*)d_in[1];
    float* out = (float*)d_out;
    float* partials = (float*)d_ws;

    int ncells = in_sizes[0] / 30;                       // 802816
    int grid = (ncells + NT * TILE - 1) / (NT * TILE);   // 1568

    yolo_loss_kernel<<<grid, 256, 0, stream>>>(preds, targets, partials, ncells);
    yolo_reduce_kernel<<<1, 256, 0, stream>>>(partials, out, grid);
}